// Round 13
// baseline (161.587 us; speedup 1.0000x reference)
//
#include <hip/hip_runtime.h>

#define D 300
#define HDIM 512
#define ROWSB 128         // X rows per block (grid 512 = 2 blocks/CU)
#define WPB 64            // words per block
#define NKS 19            // K-steps of 16 (304: 300 data + ones@300 + pad)
#define CH_BYTES 19456    // one 32-col W chunk: 19 ks * 1024 B
#define CH_ELEMS 9728
#define XSTR 19456        // X LDS stride per row-group

typedef __attribute__((ext_vector_type(16))) float f32x16;
typedef __attribute__((ext_vector_type(4))) float f32x4;
typedef __attribute__((ext_vector_type(8))) short bf16x8;

__device__ inline unsigned short f2bf(float f) {
  unsigned int u = __float_as_uint(f);
  unsigned int r = (u + 0x7fffu + ((u >> 16) & 1u)) >> 16;
  return (unsigned short)r;
}

// 48 chunks of 32 cols: 0-15 Wq, 16-31 Wk, 32-47 Wv. Chunk layout
// [ks19][kh2][col32][e8] (R10-verified conflict-free/coalesced). k<300 = W,
// k==300 = BIAS row (ones-feature folds bias into the matmul), k>300 = 0.
__global__ __launch_bounds__(512) void prep_weights(
    const float* __restrict__ Wq, const float* __restrict__ Wk,
    const float* __restrict__ Wv, const float* __restrict__ bq,
    const float* __restrict__ bk, const float* __restrict__ bv,
    unsigned short* __restrict__ wt) {
  int idx = blockIdx.x * 512 + threadIdx.x;
  if (idx >= 48 * CH_ELEMS) return;
  int c = idx / CH_ELEMS, r2 = idx - c * CH_ELEMS;
  int ks = r2 >> 9, r3 = r2 & 511;
  int kh = r3 >> 8, r4 = r3 & 255;
  int col = r4 >> 3, e = r4 & 7;
  int k = ks * 16 + kh * 8 + e;
  const float* M; const float* B; int gcol;
  if (c < 16)      { M = Wq; B = bq; gcol = c * 32 + col; }
  else if (c < 32) { M = Wk; B = bk; gcol = (c - 16) * 32 + col; }
  else             { M = Wv; B = bv; gcol = (c - 32) * 32 + col; }
  float v = (k < D) ? M[k * HDIM + gcol] : ((k == D) ? B[gcol] : 0.0f);
  wt[idx] = f2bf(v);
}

// Inverted dataflow: A = weight panels (152 VGPR, global->reg, L2-resident),
// B = X from LDS (staged once, conflict-free). Each X ds_read feeds 2 MFMAs
// -> LDS-read pipe ~23us < MFMA floor 24.5us. NO barriers in compute loops.
// NOTE: no 2nd __launch_bounds__ arg (R4-R6: halves VGPR pool -> spill).
__global__ __launch_bounds__(256) void fused_attn(
    const float* __restrict__ charv, const float* __restrict__ wordv,
    const unsigned short* __restrict__ wt, float* __restrict__ out) {
  extern __shared__ char lds[];
  float* sS  = (float*)(lds + 4 * XSTR);          // [2][64][4 wave] = 2048 B
  float* sAt = (float*)(lds + 4 * XSTR + 2048);   // [64 w][4] = 1024 B

  const int tid  = threadIdx.x;
  const int wid  = tid >> 6;    // 0..3
  const int lane = tid & 63;
  const int lo5  = lane & 31;
  const int hi   = lane >> 5;
  const int g0   = blockIdx.x * WPB;

  // ---- stage X: 128 rows x 304 k -> bf16 LDS [rg][ks][kh][row32][e8];
  // k==300 -> 1.0 (ones-feature for bias), k>300 -> 0.
  for (int j = tid; j < 128 * 76; j += 256) {
    int row = j / 76, q = j - row * 76;
    int k = q * 4;
    ushort4 h4;
    if (q == 75) {
      h4.x = 0x3F80; h4.y = 0; h4.z = 0; h4.w = 0;   // bf16(1.0), then pad
    } else {
      const float* rp = ((row & 1) ? charv : wordv) + (g0 + (row >> 1)) * D;
      float4 v = *(const float4*)(rp + k);
      h4.x = f2bf(v.x); h4.y = f2bf(v.y); h4.z = f2bf(v.z); h4.w = f2bf(v.w);
    }
    int addr = (row >> 5) * XSTR + (k >> 4) * 1024 + ((k >> 3) & 1) * 512
               + (row & 31) * 16 + (k & 7) * 2;
    *(ushort4*)(lds + addr) = h4;
  }
  __syncthreads();

  const int fro = hi * 512 + lo5 * 16;   // fragment offset within a ks-block

  // ---- Phase A: 4 iters; wave covers Q cols (it*4+wid)*32 and same K cols.
  float pown[4] = {0.f, 0.f, 0.f, 0.f}, pcrs[4] = {0.f, 0.f, 0.f, 0.f};
  for (int it = 0; it < 4; ++it) {
    const char* qb = (const char*)wt + (long)(it * 4 + wid) * CH_BYTES + fro;
    const char* kb = (const char*)wt + (long)(16 + it * 4 + wid) * CH_BYTES + fro;
    bf16x8 wq[NKS], wk[NKS];
#pragma unroll
    for (int ks = 0; ks < NKS; ++ks) {
      wq[ks] = *(const bf16x8*)(qb + ks * 1024);
      wk[ks] = *(const bf16x8*)(kb + ks * 1024);
    }
#pragma unroll
    for (int rg = 0; rg < 4; ++rg) {
      const char* xb = lds + rg * XSTR + fro;
      f32x16 accQ, accK;
#pragma unroll
      for (int r = 0; r < 16; ++r) { accQ[r] = 0.f; accK[r] = 0.f; }
#pragma unroll
      for (int ks = 0; ks < NKS; ++ks) {
        bf16x8 x = *(const bf16x8*)(xb + ks * 1024);
        accQ = __builtin_amdgcn_mfma_f32_32x32x16_bf16(wq[ks], x, accQ, 0, 0, 0);
        accK = __builtin_amdgcn_mfma_f32_32x32x16_bf16(wk[ks], x, accK, 0, 0, 0);
      }
      // lane holds Q/K[16 wcols, xrow=rg*32+lo5]; pair rows via shfl_xor(1)
      float down = 0.f, dcrs = 0.f;
#pragma unroll
      for (int r = 0; r < 16; ++r) {
        down += accQ[r] * accK[r];
        float ko = __shfl_xor(accK[r], 1);
        dcrs += accQ[r] * ko;
      }
      pown[rg] += down;
      pcrs[rg] += dcrs;
    }
  }
  // combine hi halves (cols split by hi)
#pragma unroll
  for (int rg = 0; rg < 4; ++rg) {
    pown[rg] += __shfl_xor(pown[rg], 32);
    pcrs[rg] += __shfl_xor(pcrs[rg], 32);
  }

  // ---- score exchange + softmax, 2 rounds of 64 rows (LDS budget)
  for (int rnd = 0; rnd < 2; ++rnd) {
    if (hi == 0) {
#pragma unroll
      for (int rr = 0; rr < 2; ++rr) {
        int rg = rnd * 2 + rr;
        int xr = rr * 32 + lo5;
        sS[xr * 4 + wid]       = pown[rg];
        sS[256 + xr * 4 + wid] = pcrs[rg];
      }
    }
    __syncthreads();
    if (tid < 32) {
      float s00 = 0.f, s01 = 0.f, s10 = 0.f, s11 = 0.f;
#pragma unroll
      for (int wv = 0; wv < 4; ++wv) {
        s00 += sS[(2 * tid) * 4 + wv];
        s11 += sS[(2 * tid + 1) * 4 + wv];
        s01 += sS[256 + (2 * tid) * 4 + wv];
        s10 += sS[256 + (2 * tid + 1) * 4 + wv];
      }
      const float sc = 0.044194173824159216f;  // 1/sqrt(512)
      s00 *= sc; s01 *= sc; s10 *= sc; s11 *= sc;
      float m0 = fmaxf(s00, s01), m1 = fmaxf(s10, s11);
      float e00 = expf(s00 - m0), e01 = expf(s01 - m0);
      float e10 = expf(s10 - m1), e11 = expf(s11 - m1);
      float i0 = 1.0f / (e00 + e01), i1 = 1.0f / (e10 + e11);
      int w = rnd * 32 + tid;
      sAt[w * 4 + 0] = e00 * i0;
      sAt[w * 4 + 1] = e01 * i0;
      sAt[w * 4 + 2] = e10 * i1;
      sAt[w * 4 + 3] = e11 * i1;
    }
    __syncthreads();
  }

  // ---- Phase B: 2 iters; wave covers V cols jt*256 + wid*64 .. +64
  for (int jt = 0; jt < 2; ++jt) {
    const int c0 = 32 + jt * 8 + wid * 2;
    const char* b0 = (const char*)wt + (long)c0 * CH_BYTES + fro;
    const char* b1 = (const char*)wt + (long)(c0 + 1) * CH_BYTES + fro;
    bf16x8 w0[NKS], w1[NKS];
#pragma unroll
    for (int ks = 0; ks < NKS; ++ks) {
      w0[ks] = *(const bf16x8*)(b0 + ks * 1024);
      w1[ks] = *(const bf16x8*)(b1 + ks * 1024);
    }
#pragma unroll
    for (int rg = 0; rg < 4; ++rg) {
      const char* xb = lds + rg * XSTR + fro;
      f32x16 a0, a1;
#pragma unroll
      for (int r = 0; r < 16; ++r) { a0[r] = 0.f; a1[r] = 0.f; }
#pragma unroll
      for (int ks = 0; ks < NKS; ++ks) {
        bf16x8 x = *(const bf16x8*)(xb + ks * 1024);
        a0 = __builtin_amdgcn_mfma_f32_32x32x16_bf16(w0[ks], x, a0, 0, 0, 0);
        a1 = __builtin_amdgcn_mfma_f32_32x32x16_bf16(w1[ks], x, a1, 0, 0, 0);
      }
      int xr = rg * 32 + lo5;
      int w = xr >> 1;
      f32x4 at = *(const f32x4*)(sAt + w * 4);
      float c_own = (xr & 1) ? at[3] : at[0];
      float c_oth = (xr & 1) ? at[2] : at[1];
      float* obase = out + (long)(g0 + w) * 1024 + (xr & 1) * 512
                     + jt * 256 + wid * 64 + 4 * hi;
#pragma unroll
      for (int set = 0; set < 2; ++set) {
        const f32x16& av = set ? a1 : a0;
#pragma unroll
        for (int qd = 0; qd < 4; ++qd) {
          float4 o;
#pragma unroll
          for (int e = 0; e < 4; ++e) {
            int r = qd * 4 + e;
            float own = av[r];
            float oth = __shfl_xor(own, 1);
            (&o.x)[e] = c_own * own + c_oth * oth;
          }
          *(float4*)(obase + set * 32 + qd * 8) = o;
        }
      }
    }
  }
}

extern "C" void kernel_launch(void* const* d_in, const int* in_sizes, int n_in,
                              void* d_out, int out_size, void* d_ws, size_t ws_size,
                              hipStream_t stream) {
  const float* charv = (const float*)d_in[0];
  const float* wordv = (const float*)d_in[1];
  const float* Wk = (const float*)d_in[2];
  const float* bk = (const float*)d_in[3];
  const float* Wq = (const float*)d_in[4];
  const float* bq = (const float*)d_in[5];
  const float* Wv = (const float*)d_in[6];
  const float* bv = (const float*)d_in[7];
  float* out = (float*)d_out;
  unsigned short* wt = (unsigned short*)d_ws;  // 48*9728*2 = 933,888 B

  prep_weights<<<48 * CH_ELEMS / 512, 512, 0, stream>>>(Wq, Wk, Wv, bq, bk, bv, wt);

  const int lds_bytes = 4 * XSTR + 2048 + 1024;  // 80,896 B -> 2 blocks/CU
  fused_attn<<<65536 / ROWSB, 256, lds_bytes, stream>>>(charv, wordv, wt, out);
}

// Round 14
// 87.961 us; speedup vs baseline: 1.8370x; 1.8370x over previous
//
#include <hip/hip_runtime.h>

#define D 300
#define HDIM 512
#define ROWS 256          // X rows per block (grid 256 = 1 block/CU)
#define WPB 128           // words per block
#define NKS 20            // K-steps of 16 (320: 300 data + bias@300 + pad)
#define NCH 24            // 16 [Q|K] chunks + 8 V chunks, 64 cols each
#define CH_BYTES 40960
#define CH_ELEMS 20480
#define REG_BYTES 20480   // 32-col region within a chunk
#define SEGW 5            // 1KB staging segments per wave per chunk

typedef __attribute__((ext_vector_type(16))) float f32x16;
typedef __attribute__((ext_vector_type(4))) float f32x4;
typedef __attribute__((ext_vector_type(8))) short bf16x8;

__device__ inline unsigned short f2bf(float f) {
  unsigned int u = __float_as_uint(f);
  unsigned int r = (u + 0x7fffu + ((u >> 16) & 1u)) >> 16;
  return (unsigned short)r;
}

__device__ inline void gload_lds16(const void* g, void* l) {
  __builtin_amdgcn_global_load_lds(
      (const __attribute__((address_space(1))) unsigned int*)g,
      (__attribute__((address_space(3))) unsigned int*)l, 16, 0, 0);
}

// R10 layout + bias-as-feature: chunk = [regionA][regionB], region =
// [ks20][kh2][col32][e8]; lane's B-frag = contiguous 1KB (conflict-free,
// R10-verified 7.9M->24K). k<300 = W, k==300 = bias row (ones-feature),
// k>300 = 0.  c<16: A=Wq/bq cols c*32, B=Wk/bk cols c*32; c>=16: Wv/bv.
__global__ __launch_bounds__(512) void prep_weights(
    const float* __restrict__ Wq, const float* __restrict__ Wk,
    const float* __restrict__ Wv, const float* __restrict__ bq,
    const float* __restrict__ bk, const float* __restrict__ bv,
    unsigned short* __restrict__ wt) {
  int idx = blockIdx.x * 512 + threadIdx.x;
  if (idx >= NCH * CH_ELEMS) return;
  int c = idx / CH_ELEMS, r = idx - c * CH_ELEMS;
  int reg = r / 10240, r2 = r - reg * 10240;
  int ks = r2 >> 9, r3 = r2 & 511;
  int kh = r3 >> 8, r4 = r3 & 255;
  int col = r4 >> 3, e = r4 & 7;
  int k = ks * 16 + kh * 8 + e;
  const float* M; const float* B; int gcol;
  if (c < 16) {
    M = reg ? Wk : Wq; B = reg ? bk : bq; gcol = c * 32 + col;
  } else {
    M = Wv; B = bv; gcol = (c - 16) * 64 + reg * 32 + col;
  }
  float v = (k < D) ? M[k * HDIM + gcol] : ((k == D) ? B[gcol] : 0.0f);
  wt[idx] = f2bf(v);
}

// R10 + T5 setprio + ones-bias + stage-first prologue.
// NOTE: no 2nd __launch_bounds__ arg (R4-R6: halves VGPR pool -> spill).
__global__ __launch_bounds__(512) void fused_attn(
    const float* __restrict__ charv, const float* __restrict__ wordv,
    const unsigned short* __restrict__ wt, float* __restrict__ out) {
  extern __shared__ char lds[];
  float* sS  = (float*)(lds + 3 * CH_BYTES);  // [128 w][4]; reused as sAt
  float* sAt = sS;                            // aliased (per-thread R->W, barrier-sep)

  const int tid  = threadIdx.x;
  const int wid  = tid >> 6;
  const int lane = tid & 63;
  const int lo5  = lane & 31;
  const int hi   = lane >> 5;

  auto stage = [&](int t) {
    const char* src = (const char*)wt + (long)t * CH_BYTES + wid * (SEGW * 1024) + lane * 16;
    char* dst = lds + (t % 3) * CH_BYTES + wid * (SEGW * 1024);
#pragma unroll
    for (int j = 0; j < SEGW; ++j)
      gload_lds16(src + j * 1024, dst + j * 1024);
  };

  // ---- prologue: stage 0,1 FIRST (weights land under X-load latency)
  stage(0);
  stage(1);

  // A-frag: lane holds A[row=lo5][k=ks*16+hi*8+e]; wave rows wid*32..+32.
  // Ones-feature: k==300 (ks=18,hi=1,e=4) = 1.0 -> bias folds into matmul.
  bf16x8 a[NKS];
  {
    int row = blockIdx.x * ROWS + wid * 32 + lo5;
    const float* rp = ((row & 1) ? charv : wordv) + (row >> 1) * D;
#pragma unroll
    for (int ks = 0; ks < NKS; ++ks) {
      int k0 = ks * 16 + hi * 8;
      float4 lo = {0.f, 0.f, 0.f, 0.f}, hif = {0.f, 0.f, 0.f, 0.f};
      if (k0 + 8 <= D) {
        lo  = *(const float4*)(rp + k0);
        hif = *(const float4*)(rp + k0 + 4);
      } else if (k0 < D) {
        lo  = *(const float4*)(rp + k0);
      }
      bf16x8 v;
      v[0] = (short)f2bf(lo.x);  v[1] = (short)f2bf(lo.y);
      v[2] = (short)f2bf(lo.z);  v[3] = (short)f2bf(lo.w);
      v[4] = (short)f2bf(hif.x); v[5] = (short)f2bf(hif.y);
      v[6] = (short)f2bf(hif.z); v[7] = (short)f2bf(hif.w);
      if (ks == 18 && hi == 1) v[4] = (short)0x3F80;  // bf16(1.0) at k=300
      a[ks] = v;
    }
  }

  // score partials: p[tt*4 + i*2 + j] for word-pair slot tt (8 words/lane)
  float p[32];
#pragma unroll
  for (int t = 0; t < 32; ++t) p[t] = 0.f;

  // ---- Phase A: 16 [Q|K] chunks, counted vmcnt, 1 barrier each
  for (int t = 0; t < 16; ++t) {
    asm volatile("s_waitcnt vmcnt(5)" ::: "memory");    // stage(t) landed; t+1 in flight
    asm volatile("s_waitcnt lgkmcnt(0)" ::: "memory");
    __builtin_amdgcn_s_barrier();
    stage(t + 2);
    const char* base = lds + (t % 3) * CH_BYTES + hi * 512 + lo5 * 16;
    f32x16 accQ, accK;
#pragma unroll
    for (int r = 0; r < 16; ++r) { accQ[r] = 0.f; accK[r] = 0.f; }
    __builtin_amdgcn_s_setprio(1);
#pragma unroll
    for (int ks = 0; ks < NKS; ++ks) {
      bf16x8 qb = *(const bf16x8*)(base + ks * 1024);
      bf16x8 kb = *(const bf16x8*)(base + REG_BYTES + ks * 1024);
      accQ = __builtin_amdgcn_mfma_f32_32x32x16_bf16(a[ks], qb, accQ, 0, 0, 0);
      accK = __builtin_amdgcn_mfma_f32_32x32x16_bf16(a[ks], kb, accK, 0, 0, 0);
    }
    __builtin_amdgcn_s_setprio(0);
    // lane-local: regs (2tt,2tt+1) = rows of word w = wid*16+(tt>>1)*4+(tt&1)+hi*2
#pragma unroll
    for (int tt = 0; tt < 8; ++tt)
#pragma unroll
      for (int i = 0; i < 2; ++i)
#pragma unroll
        for (int j = 0; j < 2; ++j)
          p[tt * 4 + i * 2 + j] += accQ[2 * tt + i] * accK[2 * tt + j];
  }

  // ---- reduce over 32 col-lanes (masks keep hi fixed), write scores
#pragma unroll
  for (int t = 0; t < 32; ++t) {
    float v = p[t];
    v += __shfl_xor(v, 1);
    v += __shfl_xor(v, 2);
    v += __shfl_xor(v, 4);
    v += __shfl_xor(v, 8);
    v += __shfl_xor(v, 16);
    p[t] = v;
  }
  if (lo5 == 0) {
#pragma unroll
    for (int tt = 0; tt < 8; ++tt) {
      int w = wid * 16 + (tt >> 1) * 4 + (tt & 1) + hi * 2;
#pragma unroll
      for (int q = 0; q < 4; ++q) sS[w * 4 + q] = p[tt * 4 + q];
    }
  }
  asm volatile("s_waitcnt lgkmcnt(0)" ::: "memory");
  __builtin_amdgcn_s_barrier();
  if (tid < 128) {
    const float sc = 0.044194173824159216f;  // 1/sqrt(512)
    float s[4];
#pragma unroll
    for (int t = 0; t < 4; ++t) s[t] = sS[tid * 4 + t] * sc;
#pragma unroll
    for (int i = 0; i < 2; ++i) {
      float m  = fmaxf(s[i * 2], s[i * 2 + 1]);
      float e0 = expf(s[i * 2] - m), e1 = expf(s[i * 2 + 1] - m);
      float inv = 1.0f / (e0 + e1);
      sAt[tid * 4 + i * 2]     = e0 * inv;
      sAt[tid * 4 + i * 2 + 1] = e1 * inv;
    }
  }
  asm volatile("s_waitcnt lgkmcnt(0)" ::: "memory");
  __builtin_amdgcn_s_barrier();

  // attention weights for this lane's 8 words
  f32x4 at[8];
#pragma unroll
  for (int tt = 0; tt < 8; ++tt) {
    int w = wid * 16 + (tt >> 1) * 4 + (tt & 1) + hi * 2;
    at[tt] = *(const f32x4*)(sAt + w * 4);
  }

  // ---- Phase B: 8 V chunks; vmcnt(37) = 5 stage + 32 stores newer
  for (int t = 16; t < NCH; ++t) {
    if (t == 16) asm volatile("s_waitcnt vmcnt(5)" ::: "memory");
    else         asm volatile("s_waitcnt vmcnt(37)" ::: "memory");
    asm volatile("s_waitcnt lgkmcnt(0)" ::: "memory");
    __builtin_amdgcn_s_barrier();
    if (t + 2 < NCH) stage(t + 2);
    const char* base = lds + (t % 3) * CH_BYTES + hi * 512 + lo5 * 16;
    const int g = t - 16;
#pragma unroll
    for (int ct = 0; ct < 2; ++ct) {
      f32x16 accV;
#pragma unroll
      for (int r = 0; r < 16; ++r) accV[r] = 0.f;
      __builtin_amdgcn_s_setprio(1);
#pragma unroll
      for (int ks = 0; ks < NKS; ++ks) {
        bf16x8 vb = *(const bf16x8*)(base + ct * REG_BYTES + ks * 1024);
        accV = __builtin_amdgcn_mfma_f32_32x32x16_bf16(a[ks], vb, accV, 0, 0, 0);
      }
      __builtin_amdgcn_s_setprio(0);
      int h = g * 64 + ct * 32 + lo5;
#pragma unroll
      for (int tt = 0; tt < 8; ++tt) {
        int w = wid * 16 + (tt >> 1) * 4 + (tt & 1) + hi * 2;
        long gw = (long)(blockIdx.x * WPB + w);
        float v0 = accV[2 * tt], v1 = accV[2 * tt + 1];
        out[gw * 1024 + h]       = at[tt][0] * v0 + at[tt][1] * v1;
        out[gw * 1024 + 512 + h] = at[tt][2] * v0 + at[tt][3] * v1;
      }
    }
  }
}

extern "C" void kernel_launch(void* const* d_in, const int* in_sizes, int n_in,
                              void* d_out, int out_size, void* d_ws, size_t ws_size,
                              hipStream_t stream) {
  const float* charv = (const float*)d_in[0];
  const float* wordv = (const float*)d_in[1];
  const float* Wk = (const float*)d_in[2];
  const float* bk = (const float*)d_in[3];
  const float* Wq = (const float*)d_in[4];
  const float* bq = (const float*)d_in[5];
  const float* Wv = (const float*)d_in[6];
  const float* bv = (const float*)d_in[7];
  float* out = (float*)d_out;
  unsigned short* wt = (unsigned short*)d_ws;  // 24*20480*2 = 983,040 B

  prep_weights<<<(NCH * CH_ELEMS + 511) / 512, 512, 0, stream>>>(
      Wq, Wk, Wv, bq, bk, bv, wt);

  const int lds_bytes = 3 * CH_BYTES + 512 * 4;  // 124,928 B
  fused_attn<<<65536 / ROWS, 512, lds_bytes, stream>>>(charv, wordv, wt, out);
}